// Round 4
// baseline (913.591 us; speedup 1.0000x reference)
//
#include <hip/hip_runtime.h>

// DeepCNF: 5x conv1d(K=11)+tanh -> 1x1 conv to 8 tags -> CRF NLL (sum over batch).
// B=128 T=1024 IN=42 HID=256 K=11 NTAGS=8.
// Inter-layer H format: bf16, row = (b*T+t)*256 shorts, within-row 16B chunks
// stored at position (chunk ^ (t&7)) -- global_load_lds (linear dest) +
// XOR-swizzled ds_read_b128 is conflict-free (both-sides swizzle).
// Weights packed in it = cic*11 + k order so the conv inner loop needs one
// runtime LDS address per iter (tf/k offsets fold into ds immediates).
// conv4 epilogue computes emissions directly (atomicAdd into zeroed em);
// b_out is folded into the CRF kernels.
// CRF: log-semiring segment matrix products (32 segments of 32 steps).

#define B_ 128
#define T_ 1024
#define IN_DIM_ 42
#define HID_ 256
#define KW_ 11
#define NTAGS_ 8
#define SEG_ 32
#define SEGL_ (T_ / SEG_)   // 32

typedef __bf16 bf16x8 __attribute__((ext_vector_type(8)));
typedef float f32x4 __attribute__((ext_vector_type(4)));
typedef short s16x8 __attribute__((ext_vector_type(8)));

__device__ __forceinline__ unsigned short f2bf(float f) {
    unsigned u = __builtin_bit_cast(unsigned, f);
    u += 0x7FFFu + ((u >> 16) & 1u);   // RNE
    return (unsigned short)(u >> 16);
}
__device__ __forceinline__ float bf2f(unsigned short h) {
    unsigned u = ((unsigned)h) << 16;
    return __builtin_bit_cast(float, u);
}
__device__ __forceinline__ float fast_tanh(float x) {
    float e = __expf(2.f * x);          // inf/0 saturate to +-1 correctly
    return 1.f - 2.f / (e + 1.f);
}

// ---------------------------------------------------------------------------
// Pack conv weights (C_out=256, C_in, K=11) fp32 -> bf16 MFMA B-fragments,
// fragment-group order it = cic*KW + k:
// wp[((it*16+coc)*64+lane)*8+e] = w[coc*16+(lane&15)][cic*32+(lane>>4)*8+e][k]
// ---------------------------------------------------------------------------
__global__ void pack_kernel(const float* __restrict__ w, int C_in,
                            unsigned short* __restrict__ wp, int total) {
    for (int idx = blockIdx.x * 256 + threadIdx.x; idx < total;
         idx += gridDim.x * 256) {
        int e    = idx & 7;
        int lane = (idx >> 3) & 63;
        int coc  = (idx >> 9) & 15;
        int rest = idx >> 13;          // it = cic*KW_ + k
        int cic  = rest / KW_;
        int k    = rest - cic * KW_;
        int co = coc * 16 + (lane & 15);
        int ci = cic * 32 + (lane >> 4) * 8 + e;
        float v = (ci < C_in) ? w[(co * C_in + ci) * KW_ + k] : 0.f;
        wp[idx] = f2bf(v);
    }
}

// ---------------------------------------------------------------------------
// Conv layer, implicit GEMM. Block = (batch b, 128 t) x 256 co, 8 waves =
// 2 t-halves x 4 co-quarters; wave tile 64t x 64co, 16x16x32 MFMA.
// LAST: skip H write; fuse emission projection (shfl-reduce + atomicAdd em).
// ---------------------------------------------------------------------------
template <int CIN, bool FIRST, bool LAST>
__global__ __launch_bounds__(512, 4)
void conv_kernel(const void* __restrict__ in_, const unsigned short* __restrict__ wpack,
                 const float* __restrict__ bias, unsigned short* __restrict__ out,
                 const float* __restrict__ w_out, float* __restrict__ emout) {
    constexpr int NCIC = CIN / 32;          // 2 or 8
    constexpr int ROWS = 138;               // 128 + 2*5 halo
    extern __shared__ unsigned short lds[]; // [ROWS][CIN]

    const int tid  = threadIdx.x;
    const int wave = tid >> 6;
    const int lane = tid & 63;
    const int l15  = lane & 15;
    const int lhi  = lane >> 4;
    const int wr   = wave >> 2;             // t-half
    const int wc   = wave & 3;              // co-quarter
    const int b    = blockIdx.x >> 3;
    const int t0   = (blockIdx.x & 7) * 128;

    if (FIRST) {
        const float* x = (const float*)in_;
        for (int u = tid; u < ROWS * (CIN / 8); u += 512) {
            int r = u >> 3, c = u & (CIN / 8 - 1);
            int gt = t0 - 5 + r;
            s16x8 v = {0, 0, 0, 0, 0, 0, 0, 0};
            if (gt >= 0 && gt < T_) {
#pragma unroll
                for (int j = 0; j < 8; ++j) {
                    int ci = c * 8 + j;
                    v[j] = (ci < IN_DIM_)
                               ? (short)f2bf(x[((size_t)b * T_ + gt) * IN_DIM_ + ci])
                               : (short)0;
                }
            }
            int p = c ^ ((r + 3) & 7);
            *(s16x8*)&lds[r * CIN + p * 8] = v;
        }
        __syncthreads();
    } else {
        const unsigned short* Hin = (const unsigned short*)in_;
        for (int r0 = wave * 2; r0 < ROWS; r0 += 16) {
            int r  = r0 + (lane >> 5);
            int gt = t0 - 5 + r;
            gt = gt < 0 ? 0 : (gt >= T_ ? T_ - 1 : gt);   // clamp; zeroed below
            const unsigned short* src =
                Hin + ((size_t)b * T_ + gt) * CIN + (lane & 31) * 8;
            __builtin_amdgcn_global_load_lds(
                (const __attribute__((address_space(1))) void*)src,
                (__attribute__((address_space(3))) void*)&lds[r0 * CIN], 16, 0, 0);
        }
        __syncthreads();
        if (t0 == 0) {
            for (int u = tid; u < 5 * (CIN / 2); u += 512)
                ((unsigned*)lds)[u] = 0;                  // rows 0..4
        }
        if (t0 == T_ - 128) {
            for (int u = tid; u < 5 * (CIN / 2); u += 512)
                ((unsigned*)&lds[133 * CIN])[u] = 0;      // rows 133..137
        }
        __syncthreads();
    }

    f32x4 acc[4][4];
#pragma unroll
    for (int tf = 0; tf < 4; ++tf)
#pragma unroll
        for (int n = 0; n < 4; ++n) acc[tf][n] = (f32x4){0.f, 0.f, 0.f, 0.f};

    // B fragment (it, n) at wpIt[it*8192 + n*512]
    const unsigned short* wpIt = wpack + (size_t)(wc * 4) * 512 + lane * 8;
    const int arow = (wr * 64 + l15) * CIN;   // LDS base row (shorts)
    const int l153 = l15 + 3;

    s16x8 Bf0[4], Bf1[4];
#pragma unroll
    for (int n = 0; n < 4; ++n) Bf0[n] = *(const s16x8*)&wpIt[n * 512];

#define PREF(BUF, nkk)                                                         \
    {                                                                          \
        _Pragma("unroll") for (int n = 0; n < 4; ++n) BUF[n] =                 \
            *(const s16x8*)&wpIt[(nkk) * 8192 + n * 512];                      \
    }

#define CMP(BUF, kk)                                                           \
    {                                                                          \
        const int k_ = (kk) % KW_;                                             \
        const int q_ = q0 + ((kk) / KW_) * 4;                                  \
        int key_ = (l153 + k_) & 7;                                            \
        int ao_  = arow + ((q_ ^ key_) << 3);                                  \
        s16x8 a0 = *(const s16x8*)&lds[ao_ + (0 * 16 + k_) * CIN];             \
        s16x8 a1 = *(const s16x8*)&lds[ao_ + (1 * 16 + k_) * CIN];             \
        s16x8 a2 = *(const s16x8*)&lds[ao_ + (2 * 16 + k_) * CIN];             \
        s16x8 a3 = *(const s16x8*)&lds[ao_ + (3 * 16 + k_) * CIN];             \
        __builtin_amdgcn_s_setprio(1);                                         \
        _Pragma("unroll") for (int n = 0; n < 4; ++n) {                        \
            bf16x8 bb = __builtin_bit_cast(bf16x8, BUF[n]);                    \
            acc[0][n] = __builtin_amdgcn_mfma_f32_16x16x32_bf16(               \
                __builtin_bit_cast(bf16x8, a0), bb, acc[0][n], 0, 0, 0);       \
            acc[1][n] = __builtin_amdgcn_mfma_f32_16x16x32_bf16(               \
                __builtin_bit_cast(bf16x8, a1), bb, acc[1][n], 0, 0, 0);       \
            acc[2][n] = __builtin_amdgcn_mfma_f32_16x16x32_bf16(               \
                __builtin_bit_cast(bf16x8, a2), bb, acc[2][n], 0, 0, 0);       \
            acc[3][n] = __builtin_amdgcn_mfma_f32_16x16x32_bf16(               \
                __builtin_bit_cast(bf16x8, a3), bb, acc[3][n], 0, 0, 0);       \
        }                                                                      \
        __builtin_amdgcn_s_setprio(0);                                         \
    }

    int q0 = lhi;
    for (int cic2 = 0; cic2 < NCIC; cic2 += 2) {
#pragma unroll
        for (int kk = 0; kk < 2 * KW_; ++kk) {
            if ((kk & 1) == 0) {
                PREF(Bf1, kk + 1);
                CMP(Bf0, kk);
            } else {
                PREF(Bf0, kk + 1);   // kk==21 -> next cic2's it0 (or tail slack)
                CMP(Bf1, kk);
            }
        }
        wpIt += 2 * KW_ * 8192;
        q0 += 8;
    }
#undef PREF
#undef CMP

    if constexpr (!LAST) {
        // epilogue: bias + tanh -> bf16, stored chunk-swizzled by (t&7).
#pragma unroll
        for (int n = 0; n < 4; ++n) {
            int co = wc * 64 + n * 16 + l15;
            float bv = bias[co];
#pragma unroll
            for (int tf = 0; tf < 4; ++tf) {
#pragma unroll
                for (int r4 = 0; r4 < 4; ++r4) {
                    int t = t0 + wr * 64 + tf * 16 + lhi * 4 + r4;
                    float v = fast_tanh(acc[tf][n][r4] + bv);
                    int pos = (co >> 3) ^ (t & 7);
                    out[((size_t)b * T_ + t) * HID_ + pos * 8 + (co & 7)] = f2bf(v);
                }
            }
        }
    } else {
        // fused emissions: em[b,t,tag] += sum over this wave's 64 co
        float wv[4][NTAGS_], bvn[4];
#pragma unroll
        for (int n = 0; n < 4; ++n) {
            int co = wc * 64 + n * 16 + l15;
            bvn[n] = bias[co];
#pragma unroll
            for (int tg = 0; tg < NTAGS_; ++tg) wv[n][tg] = w_out[tg * HID_ + co];
        }
#pragma unroll
        for (int tf = 0; tf < 4; ++tf) {
#pragma unroll
            for (int r4 = 0; r4 < 4; ++r4) {
                float h[4];
#pragma unroll
                for (int n = 0; n < 4; ++n)
                    h[n] = fast_tanh(acc[tf][n][r4] + bvn[n]);
                float pt[NTAGS_];
#pragma unroll
                for (int tg = 0; tg < NTAGS_; ++tg)
                    pt[tg] = h[0] * wv[0][tg] + h[1] * wv[1][tg] +
                             h[2] * wv[2][tg] + h[3] * wv[3][tg];
#pragma unroll
                for (int off = 8; off; off >>= 1)
#pragma unroll
                    for (int tg = 0; tg < NTAGS_; ++tg)
                        pt[tg] += __shfl_down(pt[tg], off);
                if (l15 == 0) {
                    int t = t0 + wr * 64 + tf * 16 + lhi * 4 + r4;
#pragma unroll
                    for (int tg = 0; tg < NTAGS_; ++tg)
                        atomicAdd(&emout[((size_t)b * T_ + t) * NTAGS_ + tg], pt[tg]);
                }
            }
        }
    }
}

// ---------------------------------------------------------------------------
// CRF segment kernel: wave per (b, s). Lane (i=lane>>3, j=lane&7) holds
// M[i][j], lse-product of S_t[i][j] = tr[i][j] + em[b,t,j] + bo[j] over the
// segment (segment 0 starts at t=1).
// ---------------------------------------------------------------------------
__global__ __launch_bounds__(256)
void crf_seg_kernel(const float* __restrict__ em, const float* __restrict__ tr,
                    const float* __restrict__ bo, float* __restrict__ segM) {
    const int gw   = blockIdx.x * 4 + (threadIdx.x >> 6);
    const int b    = gw >> 5;
    const int s    = gw & 31;
    const int lane = threadIdx.x & 63;
    const int i    = lane >> 3;
    const int j    = lane & 7;
    const float* emb = em + (size_t)b * T_ * NTAGS_;
    const float boj = bo[j];

    float tc[8];
#pragma unroll
    for (int k = 0; k < 8; ++k) tc[k] = tr[k * 8 + j];

    const int tb = (s == 0) ? 1 : s * SEGL_;
    const int te = (s + 1) * SEGL_;

    float m = tr[i * 8 + j] + emb[tb * 8 + j] + boj;
    for (int t = tb + 1; t < te; ++t) {
        float emt = emb[t * 8 + j] + boj;
        float v[8];
#pragma unroll
        for (int k = 0; k < 8; ++k) v[k] = __shfl(m, (lane & 56) + k) + tc[k];
        float mx = fmaxf(fmaxf(fmaxf(v[0], v[1]), fmaxf(v[2], v[3])),
                         fmaxf(fmaxf(v[4], v[5]), fmaxf(v[6], v[7])));
        float sm = 0.f;
#pragma unroll
        for (int k = 0; k < 8; ++k) sm += __expf(v[k] - mx);
        m = mx + __logf(sm) + emt;
    }
    segM[(size_t)gw * 64 + lane] = m;
}

// ---------------------------------------------------------------------------
// CRF combine: one wave per batch. Numerator + 32-segment fold (segM in LDS).
// ---------------------------------------------------------------------------
__global__ __launch_bounds__(64)
void crf_kernel(const float* __restrict__ em, const float* __restrict__ segM,
                const int* __restrict__ tags,
                const float* __restrict__ st, const float* __restrict__ et,
                const float* __restrict__ tr, const float* __restrict__ bo,
                float* __restrict__ outp) {
    __shared__ float sM[SEG_ * 64];
    const int b    = blockIdx.x;
    const int lane = threadIdx.x;
    const float* emb = em + (size_t)b * T_ * NTAGS_;
    const int*   tg  = tags + (size_t)b * T_;

    for (int u = lane; u < SEG_ * 64; u += 64)
        sM[u] = segM[(size_t)b * SEG_ * 64 + u];

    const float breg = bo[lane & 7];

    float num = 0.f;
    for (int t = 1 + lane; t < T_; t += 64) {
        int pt = tg[t - 1], ct = tg[t];
        num += tr[pt * NTAGS_ + ct] + emb[t * NTAGS_ + ct] + __shfl(breg, ct);
    }
#pragma unroll
    for (int off = 32; off; off >>= 1) num += __shfl_down(num, off);
    int tgf = tg[0], tgl = tg[T_ - 1];
    float bo_f = __shfl(breg, tgf);
    float score = 0.f;
    if (lane == 0)
        score = num + st[tgf] + emb[tgf] + bo_f + et[tgl];

    __syncthreads();

    // denominator: alpha0 -> fold 32 segment matrices (j = lane&7)
    const int j = lane & 7;
    float alpha = st[j] + emb[j] + breg;
    for (int sgm = 0; sgm < SEG_; ++sgm) {
        const float* M = &sM[sgm * 64];
        float v[8];
#pragma unroll
        for (int i = 0; i < 8; ++i) v[i] = __shfl(alpha, i) + M[i * 8 + j];
        float mx = fmaxf(fmaxf(fmaxf(v[0], v[1]), fmaxf(v[2], v[3])),
                         fmaxf(fmaxf(v[4], v[5]), fmaxf(v[6], v[7])));
        float sm = 0.f;
#pragma unroll
        for (int i = 0; i < 8; ++i) sm += __expf(v[i] - mx);
        alpha = mx + __logf(sm);
    }
    float vj = alpha + et[j];
    float w[8];
#pragma unroll
    for (int i = 0; i < 8; ++i) w[i] = __shfl(vj, i);
    float m2 = w[0];
#pragma unroll
    for (int i = 1; i < 8; ++i) m2 = fmaxf(m2, w[i]);
    float s2 = 0.f;
#pragma unroll
    for (int i = 0; i < 8; ++i) s2 += __expf(w[i] - m2);
    float log_z = m2 + __logf(s2);

    if (lane == 0) atomicAdd(outp, log_z - score);
}

// ---------------------------------------------------------------------------
extern "C" void kernel_launch(void* const* d_in, const int* in_sizes, int n_in,
                              void* d_out, int out_size, void* d_ws, size_t ws_size,
                              hipStream_t stream) {
    const float* x     = (const float*)d_in[0];
    const int*   tags  = (const int*)d_in[3];
    const float* w[5]  = {(const float*)d_in[4], (const float*)d_in[6],
                          (const float*)d_in[8], (const float*)d_in[10],
                          (const float*)d_in[12]};
    const float* bias[5] = {(const float*)d_in[5], (const float*)d_in[7],
                            (const float*)d_in[9], (const float*)d_in[11],
                            (const float*)d_in[13]};
    const float* w_out = (const float*)d_in[14];
    const float* b_out = (const float*)d_in[15];
    const float* st    = (const float*)d_in[16];
    const float* et    = (const float*)d_in[17];
    const float* tr    = (const float*)d_in[18];

    // workspace layout
    unsigned short* H0 = (unsigned short*)d_ws;
    unsigned short* H1 = H0 + (size_t)B_ * T_ * HID_;
    float* em   = (float*)(H1 + (size_t)B_ * T_ * HID_);
    float* segM = em + (size_t)B_ * T_ * NTAGS_;
    unsigned short* wpbase = (unsigned short*)(segM + (size_t)B_ * SEG_ * 64);
    const int SZ0 = KW_ * 2 * 16 * 512;   // layer 0 (C_in pad 64)
    const int SZN = KW_ * 8 * 16 * 512;   // layers 1..4 (C_in 256)
    unsigned short* wp[5];
    wp[0] = wpbase;
    wp[1] = wp[0] + SZ0;
    wp[2] = wp[1] + SZN;
    wp[3] = wp[2] + SZN;
    wp[4] = wp[3] + SZN;
    // (+16K shorts tail slack after wp[4] for the last B prefetch)

    hipFuncSetAttribute((const void*)conv_kernel<256, false, false>,
                        hipFuncAttributeMaxDynamicSharedMemorySize, 138 * 256 * 2);
    hipFuncSetAttribute((const void*)conv_kernel<256, false, true>,
                        hipFuncAttributeMaxDynamicSharedMemorySize, 138 * 256 * 2);

    hipMemsetAsync(em, 0, (size_t)B_ * T_ * NTAGS_ * 4, stream);

    pack_kernel<<<(SZ0 + 255) / 256, 256, 0, stream>>>(w[0], IN_DIM_, wp[0], SZ0);
    for (int i = 1; i < 5; ++i)
        pack_kernel<<<(SZN + 255) / 256, 256, 0, stream>>>(w[i], HID_, wp[i], SZN);

    const int NBLK = B_ * (T_ / 128);   // 1024
    conv_kernel<64, true, false><<<NBLK, 512, 138 * 64 * 2, stream>>>(
        x, wp[0], bias[0], H0, nullptr, nullptr);
    conv_kernel<256, false, false><<<NBLK, 512, 138 * 256 * 2, stream>>>(
        H0, wp[1], bias[1], H1, nullptr, nullptr);
    conv_kernel<256, false, false><<<NBLK, 512, 138 * 256 * 2, stream>>>(
        H1, wp[2], bias[2], H0, nullptr, nullptr);
    conv_kernel<256, false, false><<<NBLK, 512, 138 * 256 * 2, stream>>>(
        H0, wp[3], bias[3], H1, nullptr, nullptr);
    conv_kernel<256, false, true><<<NBLK, 512, 138 * 256 * 2, stream>>>(
        H1, wp[4], bias[4], nullptr, w_out, em);

    crf_seg_kernel<<<B_ * SEG_ / 4, 256, 0, stream>>>(em, tr, b_out, segM);

    hipMemsetAsync(d_out, 0, sizeof(float), stream);
    crf_kernel<<<B_, 64, 0, stream>>>(em, segM, tags, st, et, tr, b_out,
                                      (float*)d_out);
}

// Round 5
// 769.019 us; speedup vs baseline: 1.1880x; 1.1880x over previous
//
#include <hip/hip_runtime.h>

// DeepCNF: 5x conv1d(K=11)+tanh -> 1x1 conv to 8 tags -> CRF NLL (sum over batch).
// B=128 T=1024 IN=42 HID=256 K=11 NTAGS=8.
// Inter-layer H format: bf16, row = (b*T+t)*256 shorts, within-row 16B chunks
// stored at position (chunk ^ (t&7)) -- global_load_lds (linear dest) +
// XOR-swizzled ds_read_b128 is conflict-free (both-sides swizzle).
// Conv block = 64 timesteps x 256 co, 4 waves (37.9KB LDS -> 4 blocks/CU).
// Weights packed it = cic*11 + k so A-tile tf/k offsets fold into ds imms.
// conv4 fuses the emission projection: LDS partial reduce, no atomics.
// CRF: log-semiring segment matrix products (32 segments of 32 steps).

#define B_ 128
#define T_ 1024
#define IN_DIM_ 42
#define HID_ 256
#define KW_ 11
#define NTAGS_ 8
#define SEG_ 32
#define SEGL_ (T_ / SEG_)   // 32

typedef __bf16 bf16x8 __attribute__((ext_vector_type(8)));
typedef float f32x4 __attribute__((ext_vector_type(4)));
typedef short s16x8 __attribute__((ext_vector_type(8)));

__device__ __forceinline__ unsigned short f2bf(float f) {
    unsigned u = __builtin_bit_cast(unsigned, f);
    u += 0x7FFFu + ((u >> 16) & 1u);   // RNE
    return (unsigned short)(u >> 16);
}
__device__ __forceinline__ float fast_tanh(float x) {
    float e = __expf(2.f * x);          // inf/0 saturate to +-1 correctly
    return 1.f - 2.f / (e + 1.f);
}

// ---------------------------------------------------------------------------
// Pack conv weights (C_out=256, C_in, K=11) fp32 -> bf16 MFMA B-fragments,
// fragment-group order it = cic*KW + k:
// wp[((it*16+coc)*64+lane)*8+e] = w[coc*16+(lane&15)][cic*32+(lane>>4)*8+e][k]
// ---------------------------------------------------------------------------
__global__ void pack_kernel(const float* __restrict__ w, int C_in,
                            unsigned short* __restrict__ wp, int total) {
    for (int idx = blockIdx.x * 256 + threadIdx.x; idx < total;
         idx += gridDim.x * 256) {
        int e    = idx & 7;
        int lane = (idx >> 3) & 63;
        int coc  = (idx >> 9) & 15;
        int rest = idx >> 13;          // it = cic*KW_ + k
        int cic  = rest / KW_;
        int k    = rest - cic * KW_;
        int co = coc * 16 + (lane & 15);
        int ci = cic * 32 + (lane >> 4) * 8 + e;
        float v = (ci < C_in) ? w[(co * C_in + ci) * KW_ + k] : 0.f;
        wp[idx] = f2bf(v);
    }
}

// ---------------------------------------------------------------------------
// Conv layer, implicit GEMM. Block = (batch b, 64 t) x 256 co, 4 waves,
// wave tile 64t x 64co (wc = wave = co-quarter). 16x16x32 MFMA, fp32 acc.
// LAST: fused emission projection via LDS partial reduce (no atomics).
// ---------------------------------------------------------------------------
template <int CIN, bool FIRST, bool LAST>
__global__ __launch_bounds__(256, 4)
void conv_kernel(const void* __restrict__ in_, const unsigned short* __restrict__ wpack,
                 const float* __restrict__ bias, unsigned short* __restrict__ out,
                 const float* __restrict__ w_out, float* __restrict__ emout) {
    constexpr int NCIC = CIN / 32;          // 2 or 8
    constexpr int ROWS = 74;                // 64 + 2*5 halo
    constexpr int TOT  = KW_ * NCIC;        // 22 or 88
    extern __shared__ unsigned short lds[]; // [ROWS][CIN]

    const int tid  = threadIdx.x;
    const int wc   = tid >> 6;              // wave = co-quarter
    const int lane = tid & 63;
    const int l15  = lane & 15;
    const int lhi  = lane >> 4;
    const int b    = blockIdx.x >> 4;
    const int t0   = (blockIdx.x & 15) * 64;

    if (FIRST) {
        const float* x = (const float*)in_;
        for (int u = tid; u < ROWS * (CIN / 8); u += 256) {
            int r = u >> 3, c = u & (CIN / 8 - 1);
            int gt = t0 - 5 + r;
            s16x8 v = {0, 0, 0, 0, 0, 0, 0, 0};
            if (gt >= 0 && gt < T_) {
#pragma unroll
                for (int j = 0; j < 8; ++j) {
                    int ci = c * 8 + j;
                    v[j] = (ci < IN_DIM_)
                               ? (short)f2bf(x[((size_t)b * T_ + gt) * IN_DIM_ + ci])
                               : (short)0;
                }
            }
            int p = c ^ ((r + 3) & 7);
            *(s16x8*)&lds[r * CIN + p * 8] = v;
        }
        __syncthreads();
    } else {
        const unsigned short* Hin = (const unsigned short*)in_;
        for (int r0 = wc * 2; r0 < ROWS; r0 += 8) {
            int r  = r0 + (lane >> 5);
            int gt = t0 - 5 + r;
            gt = gt < 0 ? 0 : (gt >= T_ ? T_ - 1 : gt);   // clamp; zeroed below
            const unsigned short* src =
                Hin + ((size_t)b * T_ + gt) * CIN + (lane & 31) * 8;
            __builtin_amdgcn_global_load_lds(
                (const __attribute__((address_space(1))) void*)src,
                (__attribute__((address_space(3))) void*)&lds[r0 * CIN], 16, 0, 0);
        }
        __syncthreads();
        if (t0 == 0) {
            for (int u = tid; u < 5 * (CIN / 2); u += 256)
                ((unsigned*)lds)[u] = 0;                  // rows 0..4
        }
        if (t0 == T_ - 64) {
            for (int u = tid; u < 5 * (CIN / 2); u += 256)
                ((unsigned*)&lds[69 * CIN])[u] = 0;       // rows 69..73
        }
        __syncthreads();
    }

    f32x4 acc[4][4];
#pragma unroll
    for (int tf = 0; tf < 4; ++tf)
#pragma unroll
        for (int n = 0; n < 4; ++n) acc[tf][n] = (f32x4){0.f, 0.f, 0.f, 0.f};

    // B fragment (it, n) at wpIt[it*8192 + n*512]
    const unsigned short* wpIt = wpack + (size_t)(wc * 4) * 512 + lane * 8;
    const int arow = l15 * CIN;
    const int l153 = l15 + 3;

    s16x8 Bf[2][4];
#pragma unroll
    for (int n = 0; n < 4; ++n) Bf[0][n] = *(const s16x8*)&wpIt[n * 512];

#pragma unroll
    for (int cic = 0; cic < NCIC; ++cic) {
#pragma unroll
        for (int k = 0; k < KW_; ++k) {
            constexpr int unused = 0; (void)unused;
            const int it = cic * KW_ + k;
            const int nx = it + 1;           // prefetch (over-reads into slack)
#pragma unroll
            for (int n = 0; n < 4; ++n)
                Bf[nx & 1][n] = *(const s16x8*)&wpIt[(size_t)nx * 8192 + n * 512];
            const int key = (l153 + k) & 7;
            const int ao  = arow + (((cic * 4 + lhi) ^ key) << 3);
            s16x8 a0 = *(const s16x8*)&lds[ao + (0 * 16 + k) * CIN];
            s16x8 a1 = *(const s16x8*)&lds[ao + (1 * 16 + k) * CIN];
            s16x8 a2 = *(const s16x8*)&lds[ao + (2 * 16 + k) * CIN];
            s16x8 a3 = *(const s16x8*)&lds[ao + (3 * 16 + k) * CIN];
            __builtin_amdgcn_s_setprio(1);
#pragma unroll
            for (int n = 0; n < 4; ++n) {
                bf16x8 bb = __builtin_bit_cast(bf16x8, Bf[it & 1][n]);
                acc[0][n] = __builtin_amdgcn_mfma_f32_16x16x32_bf16(
                    __builtin_bit_cast(bf16x8, a0), bb, acc[0][n], 0, 0, 0);
                acc[1][n] = __builtin_amdgcn_mfma_f32_16x16x32_bf16(
                    __builtin_bit_cast(bf16x8, a1), bb, acc[1][n], 0, 0, 0);
                acc[2][n] = __builtin_amdgcn_mfma_f32_16x16x32_bf16(
                    __builtin_bit_cast(bf16x8, a2), bb, acc[2][n], 0, 0, 0);
                acc[3][n] = __builtin_amdgcn_mfma_f32_16x16x32_bf16(
                    __builtin_bit_cast(bf16x8, a3), bb, acc[3][n], 0, 0, 0);
            }
            __builtin_amdgcn_s_setprio(0);
        }
    }

    if constexpr (!LAST) {
        // epilogue: bias + tanh -> bf16, stored chunk-swizzled by (t&7).
#pragma unroll
        for (int n = 0; n < 4; ++n) {
            int co = wc * 64 + n * 16 + l15;
            float bv = bias[co];
#pragma unroll
            for (int tf = 0; tf < 4; ++tf) {
#pragma unroll
                for (int r4 = 0; r4 < 4; ++r4) {
                    int t = t0 + tf * 16 + lhi * 4 + r4;
                    float v = fast_tanh(acc[tf][n][r4] + bv);
                    int pos = (co >> 3) ^ (t & 7);
                    out[((size_t)b * T_ + t) * HID_ + pos * 8 + (co & 7)] = f2bf(v);
                }
            }
        }
    } else {
        // fused emissions: partial over this wave's 64 co -> LDS -> block
        // reduce -> single coalesced store. No atomics.
        float wv[4][NTAGS_], bvn[4];
#pragma unroll
        for (int n = 0; n < 4; ++n) {
            int co = wc * 64 + n * 16 + l15;
            bvn[n] = bias[co];
#pragma unroll
            for (int tg = 0; tg < NTAGS_; ++tg) wv[n][tg] = w_out[tg * HID_ + co];
        }
        __syncthreads();                 // A-tile reads done; reuse LDS
        float* pbuf = (float*)lds;       // [4 wc][64 t][8 tg] = 8 KB
#pragma unroll
        for (int tf = 0; tf < 4; ++tf) {
#pragma unroll
            for (int r4 = 0; r4 < 4; ++r4) {
                float h[4];
#pragma unroll
                for (int n = 0; n < 4; ++n)
                    h[n] = fast_tanh(acc[tf][n][r4] + bvn[n]);
                float pt[NTAGS_];
#pragma unroll
                for (int tg = 0; tg < NTAGS_; ++tg)
                    pt[tg] = h[0] * wv[0][tg] + h[1] * wv[1][tg] +
                             h[2] * wv[2][tg] + h[3] * wv[3][tg];
#pragma unroll
                for (int off = 8; off; off >>= 1)
#pragma unroll
                    for (int tg = 0; tg < NTAGS_; ++tg)
                        pt[tg] += __shfl_down(pt[tg], off);
                if (l15 == 0) {
                    int tloc = tf * 16 + lhi * 4 + r4;
                    f32x4 lo = {pt[0], pt[1], pt[2], pt[3]};
                    f32x4 hi = {pt[4], pt[5], pt[6], pt[7]};
                    *(f32x4*)&pbuf[(wc * 64 + tloc) * 8]     = lo;
                    *(f32x4*)&pbuf[(wc * 64 + tloc) * 8 + 4] = hi;
                }
            }
        }
        __syncthreads();
        for (int u = tid; u < 64 * NTAGS_; u += 256) {
            float s = pbuf[u] + pbuf[512 + u] + pbuf[1024 + u] + pbuf[1536 + u];
            emout[((size_t)b * T_ + t0) * NTAGS_ + u] = s;
        }
    }
}

// ---------------------------------------------------------------------------
// CRF segment kernel: wave per (b, s). Lane (i=lane>>3, j=lane&7) holds
// M[i][j], lse-product of S_t[i][j] = tr[i][j] + em[b,t,j] + bo[j] over the
// segment (segment 0 starts at t=1).
// ---------------------------------------------------------------------------
__global__ __launch_bounds__(256)
void crf_seg_kernel(const float* __restrict__ em, const float* __restrict__ tr,
                    const float* __restrict__ bo, float* __restrict__ segM) {
    const int gw   = blockIdx.x * 4 + (threadIdx.x >> 6);
    const int b    = gw >> 5;
    const int s    = gw & 31;
    const int lane = threadIdx.x & 63;
    const int i    = lane >> 3;
    const int j    = lane & 7;
    const float* emb = em + (size_t)b * T_ * NTAGS_;
    const float boj = bo[j];

    float tc[8];
#pragma unroll
    for (int k = 0; k < 8; ++k) tc[k] = tr[k * 8 + j];

    const int tb = (s == 0) ? 1 : s * SEGL_;
    const int te = (s + 1) * SEGL_;

    float m = tr[i * 8 + j] + emb[tb * 8 + j] + boj;
    for (int t = tb + 1; t < te; ++t) {
        float emt = emb[t * 8 + j] + boj;
        float v[8];
#pragma unroll
        for (int k = 0; k < 8; ++k) v[k] = __shfl(m, (lane & 56) + k) + tc[k];
        float mx = fmaxf(fmaxf(fmaxf(v[0], v[1]), fmaxf(v[2], v[3])),
                         fmaxf(fmaxf(v[4], v[5]), fmaxf(v[6], v[7])));
        float sm = 0.f;
#pragma unroll
        for (int k = 0; k < 8; ++k) sm += __expf(v[k] - mx);
        m = mx + __logf(sm) + emt;
    }
    segM[(size_t)gw * 64 + lane] = m;
}

// ---------------------------------------------------------------------------
// CRF combine: one wave per batch. Numerator + 32-segment fold (segM in LDS).
// ---------------------------------------------------------------------------
__global__ __launch_bounds__(64)
void crf_kernel(const float* __restrict__ em, const float* __restrict__ segM,
                const int* __restrict__ tags,
                const float* __restrict__ st, const float* __restrict__ et,
                const float* __restrict__ tr, const float* __restrict__ bo,
                float* __restrict__ outp) {
    __shared__ float sM[SEG_ * 64];
    const int b    = blockIdx.x;
    const int lane = threadIdx.x;
    const float* emb = em + (size_t)b * T_ * NTAGS_;
    const int*   tg  = tags + (size_t)b * T_;

    for (int u = lane; u < SEG_ * 64; u += 64)
        sM[u] = segM[(size_t)b * SEG_ * 64 + u];

    const float breg = bo[lane & 7];

    float num = 0.f;
    for (int t = 1 + lane; t < T_; t += 64) {
        int pt = tg[t - 1], ct = tg[t];
        num += tr[pt * NTAGS_ + ct] + emb[t * NTAGS_ + ct] + __shfl(breg, ct);
    }
#pragma unroll
    for (int off = 32; off; off >>= 1) num += __shfl_down(num, off);
    int tgf = tg[0], tgl = tg[T_ - 1];
    float bo_f = __shfl(breg, tgf);
    float score = 0.f;
    if (lane == 0)
        score = num + st[tgf] + emb[tgf] + bo_f + et[tgl];

    __syncthreads();

    // denominator: alpha0 -> fold 32 segment matrices (j = lane&7)
    const int j = lane & 7;
    float alpha = st[j] + emb[j] + breg;
    for (int sgm = 0; sgm < SEG_; ++sgm) {
        const float* M = &sM[sgm * 64];
        float v[8];
#pragma unroll
        for (int i = 0; i < 8; ++i) v[i] = __shfl(alpha, i) + M[i * 8 + j];
        float mx = fmaxf(fmaxf(fmaxf(v[0], v[1]), fmaxf(v[2], v[3])),
                         fmaxf(fmaxf(v[4], v[5]), fmaxf(v[6], v[7])));
        float sm = 0.f;
#pragma unroll
        for (int i = 0; i < 8; ++i) sm += __expf(v[i] - mx);
        alpha = mx + __logf(sm);
    }
    float vj = alpha + et[j];
    float w[8];
#pragma unroll
    for (int i = 0; i < 8; ++i) w[i] = __shfl(vj, i);
    float m2 = w[0];
#pragma unroll
    for (int i = 1; i < 8; ++i) m2 = fmaxf(m2, w[i]);
    float s2 = 0.f;
#pragma unroll
    for (int i = 0; i < 8; ++i) s2 += __expf(w[i] - m2);
    float log_z = m2 + __logf(s2);

    if (lane == 0) atomicAdd(outp, log_z - score);
}

// ---------------------------------------------------------------------------
extern "C" void kernel_launch(void* const* d_in, const int* in_sizes, int n_in,
                              void* d_out, int out_size, void* d_ws, size_t ws_size,
                              hipStream_t stream) {
    const float* x     = (const float*)d_in[0];
    const int*   tags  = (const int*)d_in[3];
    const float* w[5]  = {(const float*)d_in[4], (const float*)d_in[6],
                          (const float*)d_in[8], (const float*)d_in[10],
                          (const float*)d_in[12]};
    const float* bias[5] = {(const float*)d_in[5], (const float*)d_in[7],
                            (const float*)d_in[9], (const float*)d_in[11],
                            (const float*)d_in[13]};
    const float* w_out = (const float*)d_in[14];
    const float* b_out = (const float*)d_in[15];
    const float* st    = (const float*)d_in[16];
    const float* et    = (const float*)d_in[17];
    const float* tr    = (const float*)d_in[18];

    // workspace layout
    unsigned short* H0 = (unsigned short*)d_ws;
    unsigned short* H1 = H0 + (size_t)B_ * T_ * HID_;
    float* em   = (float*)(H1 + (size_t)B_ * T_ * HID_);
    float* segM = em + (size_t)B_ * T_ * NTAGS_;
    unsigned short* wpbase = (unsigned short*)(segM + (size_t)B_ * SEG_ * 64);
    const int SZ0 = KW_ * 2 * 16 * 512;   // layer 0 (C_in pad 64)
    const int SZN = KW_ * 8 * 16 * 512;   // layers 1..4 (C_in 256)
    unsigned short* wp[5];
    wp[0] = wpbase;
    wp[1] = wp[0] + SZ0;
    wp[2] = wp[1] + SZN;
    wp[3] = wp[2] + SZN;
    wp[4] = wp[3] + SZN;
    // +2 fragment-groups of tail slack after wp[4] for the B prefetch overrun
    // (prefetch reads up to (TOT+1)*8192+2048 shorts past a layer's base).

    pack_kernel<<<(SZ0 + 255) / 256, 256, 0, stream>>>(w[0], IN_DIM_, wp[0], SZ0);
    for (int i = 1; i < 5; ++i)
        pack_kernel<<<(SZN + 255) / 256, 256, 0, stream>>>(w[i], HID_, wp[i], SZN);

    const int NBLK = B_ * (T_ / 64);   // 2048
    conv_kernel<64, true, false><<<NBLK, 256, 74 * 64 * 2, stream>>>(
        x, wp[0], bias[0], H0, nullptr, nullptr);
    conv_kernel<256, false, false><<<NBLK, 256, 74 * 256 * 2, stream>>>(
        H0, wp[1], bias[1], H1, nullptr, nullptr);
    conv_kernel<256, false, false><<<NBLK, 256, 74 * 256 * 2, stream>>>(
        H1, wp[2], bias[2], H0, nullptr, nullptr);
    conv_kernel<256, false, false><<<NBLK, 256, 74 * 256 * 2, stream>>>(
        H0, wp[3], bias[3], H1, nullptr, nullptr);
    conv_kernel<256, false, true><<<NBLK, 256, 74 * 256 * 2, stream>>>(
        H1, wp[4], bias[4], nullptr, w_out, em);

    crf_seg_kernel<<<B_ * SEG_ / 4, 256, 0, stream>>>(em, tr, b_out, segM);

    hipMemsetAsync(d_out, 0, sizeof(float), stream);
    crf_kernel<<<B_, 64, 0, stream>>>(em, segM, tags, st, et, tr, b_out,
                                      (float*)d_out);
}